// Round 1
// baseline (821.215 us; speedup 1.0000x reference)
//
#include <hip/hip_runtime.h>
#include <math.h>

// Problem: PREDICT_EMISSION_3D_GRID_48155173323452
// Inputs (d_in order): x[33.5M] f32, y f32, z f32, t[1], v[1], axis[3], grid[64^3] f32
// Output: emission [4096*8192] f32
//
// emission = mask * trilinear(grid, ((rodrigues(p, k, theta)+5)/10)*63),
// theta = -t*v*r^{-1.5}, constant-mode (cval=0) boundary like jax map_coordinates.

#define GR 64

// One-thread setup: derive unit rotation axis and m = -t*v into workspace.
// (Params live on device; host may not sync/copy during graph capture.)
__global__ void pe_setup(const float* __restrict__ gt, const float* __restrict__ gv,
                         const float* __restrict__ gax, float* __restrict__ ws)
{
    if (threadIdx.x == 0 && blockIdx.x == 0) {
        float t = gt[0], v = gv[0];
        float ax = gax[0], ay = gax[1], az = gax[2];
        float anorm = sqrtf(ax * ax + ay * ay + az * az);
        ws[0] = ax / anorm;   // kx
        ws[1] = ay / anorm;   // ky
        ws[2] = az / anorm;   // kz
        ws[3] = (-t) * v;     // m, matches ((-t)*v) evaluation order
    }
}

__global__ __launch_bounds__(256) void pe_main(
    const float* __restrict__ gx, const float* __restrict__ gy, const float* __restrict__ gz,
    const float* __restrict__ grid, const float* __restrict__ kws,
    float* __restrict__ out, int n4)
{
    const int tid = blockIdx.x * 256 + threadIdx.x;
    if (tid >= n4) return;

    // Uniform address -> scalar loads; 4 floats: kx,ky,kz,m
    const float kx = kws[0], ky = kws[1], kz = kws[2], m = kws[3];

    const float4 X = ((const float4*)gx)[tid];
    const float4 Y = ((const float4*)gy)[tid];
    const float4 Z = ((const float4*)gz)[tid];
    const float xs[4] = {X.x, X.y, X.z, X.w};
    const float ys[4] = {Y.x, Y.y, Y.z, Y.w};
    const float zs[4] = {Z.x, Z.y, Z.z, Z.w};
    float4 Rv;
    float* rp = &Rv.x;

#pragma unroll
    for (int j = 0; j < 4; ++j) {
        const float px = xs[j], py = ys[j], pz = zs[j];

        // theta = m * r^{-1.5}; r=0 -> rsqrt(0)=inf -> theta=-inf -> NaN after sincos
        const float r2 = px * px + py * py + pz * pz;
        const float r = sqrtf(r2);
        const float rinv15 = rsqrtf(r2 * r);   // (r^3)^{-1/2} = r^{-1.5}
        const float theta = m * rinv15;

        float st, ct;
        sincosf(theta, &st, &ct);
        const float omc = 1.0f - ct;
        const float kdp = px * kx + py * ky + pz * kz;

        // Rodrigues: p*c + (k x p)*s + k*(k.p)*(1-c)
        float nx = px * ct + (ky * pz - kz * py) * st + kx * kdp * omc;
        float ny = py * ct + (kz * px - kx * pz) * st + ky * kdp * omc;
        float nz = pz * ct + (kx * py - ky * px) * st + kz * kdp * omc;

        const bool fv0 = isfinite(nx);
        nx = fv0 ? nx : 0.0f;
        ny = isfinite(ny) ? ny : 0.0f;
        nz = isfinite(nz) ? nz : 0.0f;

        // voxel coords: (n + 5)/10 * 63
        const float cx = (nx + 5.0f) / 10.0f * 63.0f;
        const float cy = (ny + 5.0f) / 10.0f * 63.0f;
        const float cz = (nz + 5.0f) / 10.0f * 63.0f;

        const float fx = floorf(cx), fy = floorf(cy), fz = floorf(cz);
        const int ix0 = (int)fx, iy0 = (int)fy, iz0 = (int)fz;
        float wx1 = cx - fx, wy1 = cy - fy, wz1 = cz - fz;
        float wx0 = 1.0f - wx1, wy0 = 1.0f - wy1, wz0 = 1.0f - wz1;

        const int ix1 = ix0 + 1, iy1 = iy0 + 1, iz1 = iz0 + 1;
        // constant-mode boundary: clamp index, zero the weight if it was OOB
        const int ix0c = min(max(ix0, 0), GR - 1), ix1c = min(max(ix1, 0), GR - 1);
        const int iy0c = min(max(iy0, 0), GR - 1), iy1c = min(max(iy1, 0), GR - 1);
        const int iz0c = min(max(iz0, 0), GR - 1), iz1c = min(max(iz1, 0), GR - 1);
        wx0 = (ix0c == ix0) ? wx0 : 0.0f;  wx1 = (ix1c == ix1) ? wx1 : 0.0f;
        wy0 = (iy0c == iy0) ? wy0 : 0.0f;  wy1 = (iy1c == iy1) ? wy1 : 0.0f;
        wz0 = (iz0c == iz0) ? wz0 : 0.0f;  wz1 = (iz1c == iz1) ? wz1 : 0.0f;

        const float* r00 = grid + (ix0c * GR + iy0c) * GR;
        const float* r01 = grid + (ix0c * GR + iy1c) * GR;
        const float* r10 = grid + (ix1c * GR + iy0c) * GR;
        const float* r11 = grid + (ix1c * GR + iy1c) * GR;

        const float em =
            wx0 * (wy0 * (wz0 * r00[iz0c] + wz1 * r00[iz1c]) +
                   wy1 * (wz0 * r01[iz0c] + wz1 * r01[iz1c])) +
            wx1 * (wy0 * (wz0 * r10[iz0c] + wz1 * r10[iz1c]) +
                   wy1 * (wz0 * r11[iz0c] + wz1 * r11[iz1c]));

        rp[j] = fv0 ? em : 0.0f;   // final mask = isfinite(component 0)
    }

    ((float4*)out)[tid] = Rv;
}

extern "C" void kernel_launch(void* const* d_in, const int* in_sizes, int n_in,
                              void* d_out, int out_size, void* d_ws, size_t ws_size,
                              hipStream_t stream)
{
    const float* gx   = (const float*)d_in[0];
    const float* gy   = (const float*)d_in[1];
    const float* gz   = (const float*)d_in[2];
    const float* gt   = (const float*)d_in[3];
    const float* gv   = (const float*)d_in[4];
    const float* gax  = (const float*)d_in[5];
    const float* grid = (const float*)d_in[6];
    float* out = (float*)d_out;
    float* ws  = (float*)d_ws;

    const int n  = out_size;      // 4096*8192 = 33554432, divisible by 4
    const int n4 = n >> 2;

    pe_setup<<<1, 64, 0, stream>>>(gt, gv, gax, ws);
    const int blocks = (n4 + 255) / 256;
    pe_main<<<blocks, 256, 0, stream>>>(gx, gy, gz, grid, ws, out, n4);
}

// Round 2
// 484.671 us; speedup vs baseline: 1.6944x; 1.6944x over previous
//
#include <hip/hip_runtime.h>
#include <hip/hip_fp16.h>
#include <math.h>

// Problem: PREDICT_EMISSION_3D_GRID_48155173323452
// R1: replace 8 divergent fp32 gathers/point with ONE 16-B load of a
// precomputed 2x2x2 fp16 corner-cube table (4 MB in d_ws). The R0 profile
// showed both VALU (33%) and HBM (7%) idle -> TA/L1 probe-bound on the
// 268M divergent gather requests; this cuts probes 8x.

#define GR 64

// One-thread setup: unit rotation axis + m = -t*v into ws[0..3].
__global__ void pe_setup(const float* __restrict__ gt, const float* __restrict__ gv,
                         const float* __restrict__ gax, float* __restrict__ ws)
{
    if (threadIdx.x == 0 && blockIdx.x == 0) {
        float t = gt[0], v = gv[0];
        float ax = gax[0], ay = gax[1], az = gax[2];
        float anorm = sqrtf(ax * ax + ay * ay + az * az);
        ws[0] = ax / anorm;
        ws[1] = ay / anorm;
        ws[2] = az / anorm;
        ws[3] = (-t) * v;
    }
}

// Build B[ix][iy][iz] = 8 fp16 corner values {G[x+dx][y+dy][z+dz]}, dx,dy,dz in {0,1},
// neighbor indices clamped to 63 (entries needing the clamp are only read with zero
// weight or never read: main kernel bases are <= 62 per dim).
__global__ __launch_bounds__(256) void pe_build(const float* __restrict__ g,
                                                uint4* __restrict__ table)
{
    const int idx = blockIdx.x * 256 + threadIdx.x;
    if (idx >= GR * GR * GR) return;
    const int iz = idx & 63, iy = (idx >> 6) & 63, ix = idx >> 12;
    const int z1 = min(iz + 1, 63), y1 = min(iy + 1, 63), x1 = min(ix + 1, 63);
    const float* p00 = g + (ix * GR + iy) * GR;
    const float* p01 = g + (ix * GR + y1) * GR;
    const float* p10 = g + (x1 * GR + iy) * GR;
    const float* p11 = g + (x1 * GR + y1) * GR;
    __half2 h0 = __floats2half2_rn(p00[iz], p00[z1]);   // (x0,y0,z0),(x0,y0,z1)
    __half2 h1 = __floats2half2_rn(p01[iz], p01[z1]);   // (x0,y1,*)
    __half2 h2 = __floats2half2_rn(p10[iz], p10[z1]);   // (x1,y0,*)
    __half2 h3 = __floats2half2_rn(p11[iz], p11[z1]);   // (x1,y1,*)
    uint4 q;
    q.x = *(const unsigned int*)&h0;
    q.y = *(const unsigned int*)&h1;
    q.z = *(const unsigned int*)&h2;
    q.w = *(const unsigned int*)&h3;
    table[idx] = q;
}

// Per-dim: given i0 (=floor voxel), produce base b in [0,62] and weights (wA,wB)
// for table slots (b, b+1), with jax constant-mode zeroing. i0c,i1c always lie
// in {b, b+1}, so the remap is exact.
__device__ __forceinline__ void dim_weights(float c, int& b, float& wA, float& wB)
{
    const float f = floorf(c);
    const int i0 = (int)f;
    const int i1 = i0 + 1;
    float w1 = c - f;
    float w0 = 1.0f - w1;
    const int i0c = min(max(i0, 0), GR - 1);
    const int i1c = min(max(i1, 0), GR - 1);
    b = min(max(i0, 0), GR - 2);
    w0 = (i0c == i0) ? w0 : 0.0f;   // zero weight if corner was OOB
    w1 = (i1c == i1) ? w1 : 0.0f;
    wA = ((i0c == b) ? w0 : 0.0f) + ((i1c == b) ? w1 : 0.0f);
    wB = (w0 + w1) - wA;            // each weight lands on exactly one slot
}

__global__ __launch_bounds__(256) void pe_main(
    const float* __restrict__ gx, const float* __restrict__ gy, const float* __restrict__ gz,
    const uint4* __restrict__ table, const float* __restrict__ kws,
    float* __restrict__ out, int n4)
{
    const int tid = blockIdx.x * 256 + threadIdx.x;
    if (tid >= n4) return;

    const float kx = kws[0], ky = kws[1], kz = kws[2], m = kws[3];

    const float4 X = ((const float4*)gx)[tid];
    const float4 Y = ((const float4*)gy)[tid];
    const float4 Z = ((const float4*)gz)[tid];
    const float xs[4] = {X.x, X.y, X.z, X.w};
    const float ys[4] = {Y.x, Y.y, Y.z, Y.w};
    const float zs[4] = {Z.x, Z.y, Z.z, Z.w};
    float4 Rv;
    float* rp = &Rv.x;

#pragma unroll
    for (int j = 0; j < 4; ++j) {
        const float px = xs[j], py = ys[j], pz = zs[j];

        // theta = m * r^{-1.5}; r=0 -> inf -> NaN after trig (masked below)
        const float r2 = px * px + py * py + pz * pz;
        const float r = sqrtf(r2);
        const float theta = m * rsqrtf(r2 * r);

        float st, ct;
        sincosf(theta, &st, &ct);
        const float omc = 1.0f - ct;
        const float kdp = px * kx + py * ky + pz * kz;

        float nx = px * ct + (ky * pz - kz * py) * st + kx * kdp * omc;
        float ny = py * ct + (kz * px - kx * pz) * st + ky * kdp * omc;
        float nz = pz * ct + (kx * py - ky * px) * st + kz * kdp * omc;

        const bool fv0 = isfinite(nx);
        nx = fv0 ? nx : 0.0f;
        ny = isfinite(ny) ? ny : 0.0f;
        nz = isfinite(nz) ? nz : 0.0f;

        const float cx = (nx + 5.0f) / 10.0f * 63.0f;
        const float cy = (ny + 5.0f) / 10.0f * 63.0f;
        const float cz = (nz + 5.0f) / 10.0f * 63.0f;

        int bx, by, bz;
        float wxA, wxB, wyA, wyB, wzA, wzB;
        dim_weights(cx, bx, wxA, wxB);
        dim_weights(cy, by, wyA, wyB);
        dim_weights(cz, bz, wzA, wzB);

        const uint4 q = table[(bx << 12) | (by << 6) | bz];   // ONE 16-B probe
        const float2 a0 = __half22float2(*(const __half2*)&q.x);  // (x0,y0,z0/z1)
        const float2 a1 = __half22float2(*(const __half2*)&q.y);  // (x0,y1,*)
        const float2 a2 = __half22float2(*(const __half2*)&q.z);  // (x1,y0,*)
        const float2 a3 = __half22float2(*(const __half2*)&q.w);  // (x1,y1,*)

        const float z00 = wzA * a0.x + wzB * a0.y;
        const float z01 = wzA * a1.x + wzB * a1.y;
        const float z10 = wzA * a2.x + wzB * a2.y;
        const float z11 = wzA * a3.x + wzB * a3.y;

        const float em = wxA * (wyA * z00 + wyB * z01) + wxB * (wyA * z10 + wyB * z11);
        rp[j] = fv0 ? em : 0.0f;
    }

    ((float4*)out)[tid] = Rv;
}

extern "C" void kernel_launch(void* const* d_in, const int* in_sizes, int n_in,
                              void* d_out, int out_size, void* d_ws, size_t ws_size,
                              hipStream_t stream)
{
    const float* gx   = (const float*)d_in[0];
    const float* gy   = (const float*)d_in[1];
    const float* gz   = (const float*)d_in[2];
    const float* gt   = (const float*)d_in[3];
    const float* gv   = (const float*)d_in[4];
    const float* gax  = (const float*)d_in[5];
    const float* grid = (const float*)d_in[6];
    float* out = (float*)d_out;

    float* ws_params = (float*)d_ws;                        // 16 B params
    uint4* table = (uint4*)((char*)d_ws + 256);             // 4 MB corner-cube table

    const int n  = out_size;     // 33554432, divisible by 4
    const int n4 = n >> 2;

    pe_setup<<<1, 64, 0, stream>>>(gt, gv, gax, ws_params);
    pe_build<<<(GR * GR * GR) / 256, 256, 0, stream>>>(grid, table);
    pe_main<<<(n4 + 255) / 256, 256, 0, stream>>>(gx, gy, gz, table, ws_params, out, n4);
}